// Round 1
// baseline (538.904 us; speedup 1.0000x reference)
//
#include <hip/hip_runtime.h>

#define EDGES 800000
#define NODES 50000
#define CH 28        // NS + 3*NV
#define NWT 400      // n_weights

typedef __attribute__((ext_vector_type(8))) short bf16x8;
typedef __attribute__((ext_vector_type(4))) float f32x4;

__device__ __forceinline__ short f2bf(float f) {
    union { float f; unsigned u; } v; v.f = f;
    unsigned r = v.u + 0x7FFFu + ((v.u >> 16) & 1u);   // RNE
    return (short)(r >> 16);
}

// XOR swizzle for 128B-row LDS tiles (breaks 16-way conflict on b128 column reads)
#define SWZ(b, row) ((b) ^ (((row) & 7) << 4))

__global__ __launch_bounds__(256, 2) void tpconv_kernel(
    const float* __restrict__ node_attr,
    const float* __restrict__ edge_attr,
    const float* __restrict__ edge_sh,
    const int*   __restrict__ eidx,
    const float* __restrict__ W1,
    const float* __restrict__ b1,
    const float* __restrict__ W2,
    const float* __restrict__ b2,
    float* __restrict__ outacc,
    float* __restrict__ cnt)
{
    __shared__ __align__(16) short w2t[NWT * 64];   // W2^T bf16, rows n (400) x 64 j, swizzled
    __shared__ float b2s[NWT];
    __shared__ __align__(16) short hbuf[4][16 * 64]; // per-wave h tile, swizzled
    __shared__ float edata[4][16 * 53];              // per-wave per-edge coefficients
    __shared__ int   srcb[4][16];

    const int tid  = threadIdx.x;
    const int lane = tid & 63;
    const int wid  = tid >> 6;
    const int cl   = lane & 15;   // col within fragment
    const int qd   = lane >> 4;   // lane quad

    // ---- stage W2^T (bf16, swizzled) + b2 : once per block ----
    for (int f = tid; f < NWT * 64; f += 256) {
        int n = f >> 6, j = f & 63;
        int byte = SWZ(n * 128 + j * 2, n);
        w2t[byte >> 1] = f2bf(W2[j * NWT + n]);
    }
    for (int f = tid; f < NWT; f += 256) b2s[f] = b2[f];

    // ---- per-lane W1 fragments (B of GEMM1) + b1 ----
    float b1v[4];
    bf16x8 w1f[2][4];
    #pragma unroll
    for (int nt = 0; nt < 4; ++nt) {
        b1v[nt] = b1[nt * 16 + cl];
        #pragma unroll
        for (int ks = 0; ks < 2; ++ks) {
            bf16x8 fr;
            #pragma unroll
            for (int i = 0; i < 8; ++i) {
                int k = ks * 32 + qd * 8 + i;
                fr[i] = f2bf(W1[k * 64 + nt * 16 + cl]);
            }
            w1f[ks][nt] = fr;
        }
    }
    __syncthreads();

    const float INV3 = 0.57735026919f;      // 1/sqrt(3)
    const float CS_  = 0.17677669529f;      // (1/sqrt(16)) * (1/sqrt(2))
    const float CV_  = 0.35355339059f;      // (1/sqrt(4))  * (1/sqrt(2))

    const int tiles = EDGES / 16;           // 50000, exact
    for (int tile = blockIdx.x * 4 + wid; tile < tiles; tile += gridDim.x * 4) {
        const int ebase = tile * 16;

        // ---- per-edge coefficient precompute (lanes 0..15, one edge each) ----
        if (lane < 16) {
            const int e  = ebase + lane;
            const int s  = eidx[e];
            const int dn = eidx[EDGES + e];
            srcb[wid][lane] = s;
            atomicAdd(&cnt[s], 1.0f);
            const float4 sh4 = *reinterpret_cast<const float4*>(edge_sh + (size_t)e * 4);
            float xs[16], xv[12];
            {
                const float4* xp = reinterpret_cast<const float4*>(node_attr + (size_t)dn * CH);
                float4 q0 = xp[0], q1 = xp[1], q2 = xp[2], q3 = xp[3], q4 = xp[4], q5 = xp[5], q6 = xp[6];
                xs[0]=q0.x; xs[1]=q0.y; xs[2]=q0.z; xs[3]=q0.w;
                xs[4]=q1.x; xs[5]=q1.y; xs[6]=q1.z; xs[7]=q1.w;
                xs[8]=q2.x; xs[9]=q2.y; xs[10]=q2.z; xs[11]=q2.w;
                xs[12]=q3.x; xs[13]=q3.y; xs[14]=q3.z; xs[15]=q3.w;
                xv[0]=q4.x; xv[1]=q4.y; xv[2]=q4.z; xv[3]=q4.w;
                xv[4]=q5.x; xv[5]=q5.y; xv[6]=q5.z; xv[7]=q5.w;
                xv[8]=q6.x; xv[9]=q6.y; xv[10]=q6.z; xv[11]=q6.w;
            }
            const float shs = sh4.x, sv0 = sh4.y, sv1 = sh4.z, sv2 = sh4.w;
            float* ed = &edata[wid][lane * 53];
            #pragma unroll
            for (int i = 0; i < 16; ++i) {
                ed[i]      = xs[i] * shs * CS_;   // a_s  (w_ss coeff)
                ed[20 + i] = xs[i] * CS_;         // b_s  (w_sv coeff, * sh_v[d] later)
            }
            #pragma unroll
            for (int v = 0; v < 4; ++v) {
                float dot = (xv[3*v] * sv0 + xv[3*v+1] * sv1 + xv[3*v+2] * sv2) * INV3;
                ed[16 + v] = dot * CV_;           // a_v  (w_vs coeff)
                ed[36 + 3*v + 0] = xv[3*v + 0] * shs * CV_;   // xvs (w_vv coeff)
                ed[36 + 3*v + 1] = xv[3*v + 1] * shs * CV_;
                ed[36 + 3*v + 2] = xv[3*v + 2] * shs * CV_;
            }
            ed[48] = sv0; ed[49] = sv1; ed[50] = sv2;
        }

        // ---- GEMM1 A fragments straight from global (f32 -> bf16) ----
        const float4* ap = reinterpret_cast<const float4*>(edge_attr + (size_t)(ebase + cl) * 64);
        float4 a0 = ap[qd*2], a1 = ap[qd*2 + 1], a2 = ap[8 + qd*2], a3 = ap[8 + qd*2 + 1];
        bf16x8 af0, af1;
        af0[0]=f2bf(a0.x); af0[1]=f2bf(a0.y); af0[2]=f2bf(a0.z); af0[3]=f2bf(a0.w);
        af0[4]=f2bf(a1.x); af0[5]=f2bf(a1.y); af0[6]=f2bf(a1.z); af0[7]=f2bf(a1.w);
        af1[0]=f2bf(a2.x); af1[1]=f2bf(a2.y); af1[2]=f2bf(a2.z); af1[3]=f2bf(a2.w);
        af1[4]=f2bf(a3.x); af1[5]=f2bf(a3.y); af1[6]=f2bf(a3.z); af1[7]=f2bf(a3.w);

        // ---- GEMM1: h = relu(A @ W1 + b1), write bf16 h tile to LDS ----
        short* hb = hbuf[wid];
        #pragma unroll
        for (int nt = 0; nt < 4; ++nt) {
            f32x4 acc = { b1v[nt], b1v[nt], b1v[nt], b1v[nt] };
            acc = __builtin_amdgcn_mfma_f32_16x16x32_bf16(af0, w1f[0][nt], acc, 0, 0, 0);
            acc = __builtin_amdgcn_mfma_f32_16x16x32_bf16(af1, w1f[1][nt], acc, 0, 0, 0);
            #pragma unroll
            for (int r = 0; r < 4; ++r) {
                int m = qd * 4 + r;
                float hv = fmaxf(acc[r], 0.0f);
                int byte = SWZ(m * 128 + (nt * 16 + cl) * 2, m);
                hb[byte >> 1] = f2bf(hv);
            }
        }

        // ---- h fragments back (A of GEMM2); same-wave LDS, no barrier needed ----
        bf16x8 h0 = *reinterpret_cast<bf16x8*>(reinterpret_cast<char*>(hb) + SWZ(cl * 128 + qd * 16, cl));
        bf16x8 h1 = *reinterpret_cast<bf16x8*>(reinterpret_cast<char*>(hb) + SWZ(cl * 128 + 64 + qd * 16, cl));

        // ---- GEMM2 over 25 column tiles, fused tensor-product consume ----
        f32x4 outs = {0.f, 0.f, 0.f, 0.f};
        f32x4 pacc = {0.f, 0.f, 0.f, 0.f};
        float qacc[4][3] = {{0.f,0.f,0.f},{0.f,0.f,0.f},{0.f,0.f,0.f},{0.f,0.f,0.f}};
        const float* edw = edata[wid];
        const char* wb = reinterpret_cast<const char*>(w2t);
        #pragma unroll
        for (int ct = 0; ct < 25; ++ct) {
            int n = ct * 16 + cl;
            bf16x8 bf0 = *reinterpret_cast<const bf16x8*>(wb + SWZ(n * 128 + qd * 16, n));
            bf16x8 bf1 = *reinterpret_cast<const bf16x8*>(wb + SWZ(n * 128 + 64 + qd * 16, n));
            float bb = b2s[n];
            f32x4 t = { bb, bb, bb, bb };
            t = __builtin_amdgcn_mfma_f32_16x16x32_bf16(h0, bf0, t, 0, 0, 0);
            t = __builtin_amdgcn_mfma_f32_16x16x32_bf16(h1, bf1, t, 0, 0, 0);
            if (ct < 16) {                       // w_ss: out_s += a_s[row,ct] * tile
                #pragma unroll
                for (int r = 0; r < 4; ++r)
                    outs[r] += edw[(qd*4 + r) * 53 + ct] * t[r];
            } else if (ct < 20) {                // w_vs: out_s += a_v[row,ct-16] * tile
                #pragma unroll
                for (int r = 0; r < 4; ++r)
                    outs[r] += edw[(qd*4 + r) * 53 + 16 + (ct - 16)] * t[r];
            } else if (ct < 24) {                // w_sv: P partial (col c = 4*il + o)
                int il = cl >> 2;
                #pragma unroll
                for (int r = 0; r < 4; ++r)
                    pacc[r] += edw[(qd*4 + r) * 53 + 20 + 4*(ct - 20) + il] * t[r];
            } else {                             // w_vv: Q partial (col c = 4*v + o)
                int v = cl >> 2;
                #pragma unroll
                for (int r = 0; r < 4; ++r) {
                    #pragma unroll
                    for (int d = 0; d < 3; ++d)
                        qacc[r][d] += edw[(qd*4 + r) * 53 + 36 + 3*v + d] * t[r];
                }
            }
        }

        // ---- scatter out_s (16 cols x 4 rows per lane-quad) ----
        #pragma unroll
        for (int r = 0; r < 4; ++r) {
            int m = qd * 4 + r;
            int s = srcb[wid][m];
            atomicAdd(&outacc[(size_t)s * CH + cl], outs[r]);
        }
        // ---- butterfly-reduce P,Q over the 4 il/v sub-columns (lanes c, c^4, c^8) ----
        #pragma unroll
        for (int r = 0; r < 4; ++r) {
            float p = pacc[r];
            p += __shfl_xor(p, 4);
            p += __shfl_xor(p, 8);
            pacc[r] = p;
            #pragma unroll
            for (int d = 0; d < 3; ++d) {
                float q = qacc[r][d];
                q += __shfl_xor(q, 4);
                q += __shfl_xor(q, 8);
                qacc[r][d] = q;
            }
        }
        // ---- scatter out_v: lane c<12 owns (o=c&3, d=c>>2) ----
        if (cl < 12) {
            int o = cl & 3, d = cl >> 2;
            #pragma unroll
            for (int r = 0; r < 4; ++r) {
                int m = qd * 4 + r;
                int s = srcb[wid][m];
                float qv = (d == 0) ? qacc[r][0] : ((d == 1) ? qacc[r][1] : qacc[r][2]);
                float val = edw[m * 53 + 48 + d] * pacc[r] + qv;
                atomicAdd(&outacc[(size_t)s * CH + 16 + o * 3 + d], val);
            }
        }
    }
}

__global__ void finalize_kernel(float* __restrict__ out, const float* __restrict__ cnt,
                                const float* __restrict__ node_attr) {
    int idx = blockIdx.x * 256 + threadIdx.x;
    if (idx < NODES * CH) {
        int n = idx / CH;
        out[idx] = out[idx] / fmaxf(cnt[n], 1.0f) + node_attr[idx];
    }
}

extern "C" void kernel_launch(void* const* d_in, const int* in_sizes, int n_in,
                              void* d_out, int out_size, void* d_ws, size_t ws_size,
                              hipStream_t stream) {
    const float* node_attr = (const float*)d_in[0];
    const float* edge_attr = (const float*)d_in[1];
    const float* edge_sh   = (const float*)d_in[2];
    const int*   eidx      = (const int*)d_in[3];
    const float* W1 = (const float*)d_in[4];
    const float* b1 = (const float*)d_in[5];
    const float* W2 = (const float*)d_in[6];
    const float* b2 = (const float*)d_in[7];
    float* out = (float*)d_out;
    float* cnt = (float*)d_ws;

    hipMemsetAsync(d_out, 0, (size_t)NODES * CH * sizeof(float), stream);
    hipMemsetAsync(d_ws, 0, (size_t)NODES * sizeof(float), stream);
    tpconv_kernel<<<512, 256, 0, stream>>>(node_attr, edge_attr, edge_sh, eidx,
                                           W1, b1, W2, b2, out, cnt);
    finalize_kernel<<<(NODES * CH + 255) / 256, 256, 0, stream>>>(out, cnt, node_attr);
}